// Round 7
// baseline (360.916 us; speedup 1.0000x reference)
//
#include <hip/hip_runtime.h>
#include <hip/hip_bf16.h>
#include <stdint.h>

// MoE (E=16, D=1024, H=2048, K=2, T=2048), routed bf16-MFMA.
// R7 = R6 with the shuffle-layout bug fixed. Wt cell layout is
// [e][n/16][k/32][kq=4][row=16][8]: lane l of a wave reads its MFMA
// A-fragment at cell + l*8 (contiguous 1KB per fragment, sequential in k).
// GEMMs are pure register streaming: no LDS, no barriers.

#define E_ 16
#define D_ 1024
#define H_ 2048
#define K_ 2
#define T_ 2048
#define NP_ (T_ * K_)     // 4096 token-expert pairs
#define MTS_ 32           // max M-tiles at 256 granularity: 16 + 4096/256 = 32

using short8 = __attribute__((ext_vector_type(8))) short;
using f32x4  = __attribute__((ext_vector_type(4))) float;

__device__ __forceinline__ unsigned short f2bf(float f) {
  union { float f; unsigned u; } x; x.f = f;
  unsigned r = x.u + 0x7fffu + ((x.u >> 16) & 1u);   // RNE
  return (unsigned short)(r >> 16);
}

// gelu(tanh approx) = x * sigmoid(1.595769...*(x + 0.044715 x^3))
__device__ __forceinline__ float gelu_f(float x) {
  float u = 1.5957691216057308f * (x + 0.044715f * x * x * x);
  return x / (1.f + __expf(-u));
}

__global__ void cvt_kernel(const float* __restrict__ src,
                           unsigned short* __restrict__ dst, int n4) {
  int stride = gridDim.x * blockDim.x;
  for (int i = blockIdx.x * blockDim.x + threadIdx.x; i < n4; i += stride) {
    float4 v = reinterpret_cast<const float4*>(src)[i];
    ushort4 o = make_ushort4(f2bf(v.x), f2bf(v.y), f2bf(v.z), f2bf(v.w));
    reinterpret_cast<ushort4*>(dst)[i] = o;
  }
}

__global__ void route_kernel(const int* __restrict__ gidx,
                             int* __restrict__ rows,
                             int* __restrict__ offsets,
                             int2* __restrict__ tiles) {
  __shared__ int cnt[E_], cur[E_];
  int tid = threadIdx.x;
  if (tid < E_) cnt[tid] = 0;
  __syncthreads();
  for (int p = tid; p < NP_; p += blockDim.x) atomicAdd(&cnt[gidx[p]], 1);
  __syncthreads();
  if (tid == 0) {
    int acc = 0;
    for (int e = 0; e < E_; ++e) { offsets[e] = acc; cur[e] = acc; acc += cnt[e]; }
    offsets[E_] = acc;
    int2 tmp[MTS_];
    int k = 0;
    for (int e = 0; e < E_; ++e)
      for (int m = offsets[e]; m < offsets[e] + cnt[e]; m += 256)
        tmp[k++] = make_int2(e, m);
    // stride-7 scatter (7 coprime 32 -> permutation) so heavy tiles spread
    // evenly over dispatch slots -> even heavy-per-CU counts.
    for (int j = 0; j < MTS_; ++j)
      tiles[(j * 7) & 31] = (j < k) ? tmp[j] : make_int2(-1, 0);
  }
  __syncthreads();
  for (int p = tid; p < NP_; p += blockDim.x) {
    int e = gidx[p];
    int pos = atomicAdd(&cur[e], 1);
    rows[pos] = p;
  }
}

// Reshuffle W (f32, row-major [E][N][K]) -> bf16 Wt with per-(16n x 32k) cell
// layout [kq=4][row=16][8]: element (row r, k = kq*8+q) at kq*128 + r*8 + q.
// A wave's A-fragment load is then cell + lane*8 (lane = fh*16 + fr ->
// row fr, k fh*8..+7  == the m89/R1-R4-verified fragment map).
// Thread i reads 128B CONTIGUOUS (source-linear chunk order) and writes
// 4 x 16B at stride 256B within its cell.
__global__ void shuffle_w(const float* __restrict__ w1,
                          const float* __restrict__ w2,
                          unsigned short* __restrict__ wt1,
                          unsigned short* __restrict__ wt2) {
  int tid = blockIdx.x * blockDim.x + threadIdx.x;   // 0 .. 2^21-1
  const bool is1 = tid < (1 << 20);
  const float* src = is1 ? w1 : w2;
  unsigned short* dst = is1 ? wt1 : wt2;
  int rem = is1 ? tid : (tid - (1 << 20));
  int e  = rem >> 16;              // 65536 chunks per expert (both)
  int r2 = rem & 65535;
  int n, ks, NG, KS;
  if (is1) { n = r2 >> 5; ks = r2 & 31; NG = 128; KS = 32; }
  else     { n = r2 >> 6; ks = r2 & 63; NG = 64;  KS = 64; }

  const float4* s4 = reinterpret_cast<const float4*>(src + (size_t)rem * 32);
  float4 v[8];
#pragma unroll
  for (int j = 0; j < 8; ++j) v[j] = s4[j];

  // cell base + this row's 8-short slot
  size_t outoff = (((size_t)e * NG + (n >> 4)) * KS + ks) * 512 + (size_t)(n & 15) * 8;
  short8* o8 = reinterpret_cast<short8*>(dst + outoff);
#pragma unroll
  for (int j = 0; j < 4; ++j) {            // j = k-octet plane (fh)
    short8 o;
    const float* p0 = &v[2 * j].x;
    const float* p1 = &v[2 * j + 1].x;
#pragma unroll
    for (int q = 0; q < 4; ++q) { o[q] = (short)f2bf(p0[q]); o[4 + q] = (short)f2bf(p1[q]); }
    o8[j * 16] = o;                        // stride 128 shorts = one plane
  }
}

// Flat GEMM: out[wrow, tok] over one (expert, 256-token, 32-wrow) tile.
// 4 waves split tokens (64 each). A-operand = Wt fragments streamed
// contiguously (lane*16B); B-operand = act fragments gathered (L2-hot).
// D map (m89): col(lane&15) = token = fr, row = fh*4 + reg.
template<bool IS1>
__global__ __launch_bounds__(256, 3)
void moe_flat(const unsigned short* __restrict__ Act,   // xb (IS1) or h
              const unsigned short* __restrict__ Wt,    // shuffled weights
              const float* __restrict__ bias,           // [E][NN]
              const int* __restrict__ rows,
              const int* __restrict__ offsets,
              const int2* __restrict__ tiles,
              const float* __restrict__ score,          // [T*K]
              unsigned short* __restrict__ Hout,        // h (IS1)
              float* __restrict__ Yout)                 // y (!IS1)
{
  constexpr int KD = IS1 ? D_ : H_;   // contraction dim
  constexpr int NN = IS1 ? H_ : D_;   // output (weight-row) dim
  constexpr int KS = KD / 32;         // 32 or 64 k-steps
  constexpr int NG = NN / 16;

  const int2 tile = tiles[blockIdx.y];
  const int e = tile.x;
  if (e < 0) return;
  const int s0 = tile.y, send = offsets[e + 1];

  const int tid = threadIdx.x, lane = tid & 63, wid = tid >> 6;
  const int fr = lane & 15, fh = lane >> 4;

  // Two 16-row weight-fragment streams (rows blockIdx.x*32 .. +32).
  const int ng0 = blockIdx.x * 2;
  const unsigned short* wp0 =
      Wt + ((size_t)(e * NG + ng0)) * KS * 512 + lane * 8;
  const unsigned short* wp1 = wp0 + (size_t)KS * 512;

  // Four act-fragment pointers (this wave's 64 tokens; lane's token = +fr).
  int slotg[4];
  const unsigned short* ap[4];
#pragma unroll
  for (int g = 0; g < 4; ++g) {
    int s = s0 + wid * 64 + g * 16 + fr;
    slotg[g] = s;
    int cs = s < send ? s : (send - 1);
    int arow = IS1 ? (rows[cs] >> 1) : cs;
    ap[g] = Act + (size_t)arow * KD + fh * 8;
  }

  f32x4 acc[4][2] = {};
  short8 w0[2], w1r[2], a0[4], a1[4];

  auto load = [&](short8* w, short8* a, int ks) {
    w[0] = *reinterpret_cast<const short8*>(wp0 + (size_t)ks * 512);
    w[1] = *reinterpret_cast<const short8*>(wp1 + (size_t)ks * 512);
#pragma unroll
    for (int g = 0; g < 4; ++g)
      a[g] = *reinterpret_cast<const short8*>(ap[g] + ks * 32);
  };
  auto step = [&](short8* w, short8* a) {
#pragma unroll
    for (int g = 0; g < 4; ++g)
#pragma unroll
      for (int i = 0; i < 2; ++i)
        acc[g][i] = __builtin_amdgcn_mfma_f32_16x16x32_bf16(
            w[i], a[g], acc[g][i], 0, 0, 0);
  };

  load(w0, a0, 0);
  load(w1r, a1, 1);
  for (int t = 0; t < KS; t += 2) {
    step(w0, a0);
    if (t + 2 < KS) load(w0, a0, t + 2);
    step(w1r, a1);
    if (t + 3 < KS) load(w1r, a1, t + 3);
  }

  // Epilogue: lane holds 4 consecutive wrows (cb..cb+3) for its token (fr).
  const int nb = blockIdx.x * 32;
#pragma unroll
  for (int i = 0; i < 2; ++i) {
    int cb = nb + i * 16 + fh * 4;
    float4 bs = *reinterpret_cast<const float4*>(bias + (size_t)e * NN + cb);
#pragma unroll
    for (int g = 0; g < 4; ++g) {
      int slot = slotg[g];
      if (slot >= send) continue;
      if (IS1) {
        ushort4 hv;
        hv.x = f2bf(gelu_f(acc[g][i][0] + bs.x));
        hv.y = f2bf(gelu_f(acc[g][i][1] + bs.y));
        hv.z = f2bf(gelu_f(acc[g][i][2] + bs.z));
        hv.w = f2bf(gelu_f(acc[g][i][3] + bs.w));
        *reinterpret_cast<ushort4*>(Hout + (size_t)slot * H_ + cb) = hv;
      } else {
        int pair = rows[slot];
        float sc = score[pair];
        float4 yv;
        yv.x = (acc[g][i][0] + bs.x) * sc;
        yv.y = (acc[g][i][1] + bs.y) * sc;
        yv.z = (acc[g][i][2] + bs.z) * sc;
        yv.w = (acc[g][i][3] + bs.w) * sc;
        *reinterpret_cast<float4*>(Yout + (size_t)pair * D_ + cb) = yv;
      }
    }
  }
}

__global__ void combine_kernel(const float* __restrict__ y,
                               float* __restrict__ out) {
  const int DQ = D_ / 4;
  int i = blockIdx.x * blockDim.x + threadIdx.x;   // [0, T_*D_/4)
  int t = i / DQ, d = i % DQ;
  const float4* y4 = reinterpret_cast<const float4*>(y);
  float4 a = y4[(size_t)(2 * t) * DQ + d];
  float4 b = y4[(size_t)(2 * t + 1) * DQ + d];
  reinterpret_cast<float4*>(out)[i] =
      make_float4(a.x + b.x, a.y + b.y, a.z + b.z, a.w + b.w);
}

extern "C" void kernel_launch(void* const* d_in, const int* in_sizes, int n_in,
                              void* d_out, int out_size, void* d_ws, size_t ws_size,
                              hipStream_t stream) {
  const float* inp    = (const float*)d_in[0];
  const int*   gidx   = (const int*)d_in[1];
  const float* gscore = (const float*)d_in[2];
  const float* w1     = (const float*)d_in[3];
  const float* b1     = (const float*)d_in[4];
  const float* w2     = (const float*)d_in[5];
  const float* b2     = (const float*)d_in[6];
  float* out = (float*)d_out;

  char* ws = (char*)d_ws;
  size_t o = 0;
  auto alloc = [&](size_t bytes) {
    void* p = ws + o;
    o = (o + bytes + 255) & ~(size_t)255;
    return p;
  };
  unsigned short* xb   = (unsigned short*)alloc((size_t)T_ * D_ * 2);
  unsigned short* hbuf = (unsigned short*)alloc((size_t)NP_ * H_ * 2);
  float*          ybuf = (float*)alloc((size_t)NP_ * D_ * 4);
  unsigned short* wt1  = (unsigned short*)alloc((size_t)E_ * H_ * D_ * 2);
  unsigned short* wt2  = (unsigned short*)alloc((size_t)E_ * D_ * H_ * 2);
  int*            rows = (int*)alloc(NP_ * 4);
  int*         offsets = (int*)alloc((E_ + 1) * 4);
  int2*          tiles = (int2*)alloc(MTS_ * 8);

  shuffle_w<<<dim3(8192), dim3(256), 0, stream>>>(w1, w2, wt1, wt2);
  cvt_kernel<<<dim3(512), dim3(256), 0, stream>>>(inp, xb, T_ * D_ / 4);
  route_kernel<<<dim3(1), dim3(256), 0, stream>>>(gidx, rows, offsets, tiles);

  moe_flat<true><<<dim3(H_ / 32, MTS_), dim3(256), 0, stream>>>(
      xb, wt1, b1, rows, offsets, tiles, gscore, hbuf, (float*)nullptr);
  moe_flat<false><<<dim3(D_ / 32, MTS_), dim3(256), 0, stream>>>(
      hbuf, wt2, b2, rows, offsets, tiles, gscore, (unsigned short*)nullptr, ybuf);

  combine_kernel<<<dim3(T_ * D_ / 4 / 256), dim3(256), 0, stream>>>(ybuf, out);
}

// Round 8
// 196.309 us; speedup vs baseline: 1.8385x; 1.8385x over previous
//
#include <hip/hip_runtime.h>
#include <hip/hip_bf16.h>
#include <stdint.h>
#include <type_traits>

// MoE (E=16, D=1024, H=2048, K=2, T=2048), routed bf16-MFMA.
// R8 = R4 structure with a 3-deep staging pipeline: 3 LDS buffers, counted
// vmcnt(16) waits -> every tile's loads get ~2 compute-steps of flight time
// (first structure where flight >= HBM latency). 2 blocks/CU (72KB LDS).

#define E_ 16
#define D_ 1024
#define H_ 2048
#define K_ 2
#define T_ 2048
#define NP_ (T_ * K_)     // 4096 token-expert pairs
#define MTS_ 48           // max M-tiles: sum ceil(ne/128) <= 48

using short8 = __attribute__((ext_vector_type(8))) short;
using f32x4  = __attribute__((ext_vector_type(4))) float;

__device__ __forceinline__ unsigned short f2bf(float f) {
  union { float f; unsigned u; } x; x.f = f;
  unsigned r = x.u + 0x7fffu + ((x.u >> 16) & 1u);   // RNE
  return (unsigned short)(r >> 16);
}

// gelu(tanh approx) = x * sigmoid(1.595769...*(x + 0.044715 x^3))
__device__ __forceinline__ float gelu_f(float x) {
  float u = 1.5957691216057308f * (x + 0.044715f * x * x * x);
  return x / (1.f + __expf(-u));
}

__device__ __forceinline__ void waitv16() {
  asm volatile("s_waitcnt vmcnt(16)" ::: "memory");
  __builtin_amdgcn_sched_barrier(0);
}
__device__ __forceinline__ void waitv8() {
  asm volatile("s_waitcnt vmcnt(8)" ::: "memory");
  __builtin_amdgcn_sched_barrier(0);
}
__device__ __forceinline__ void waitv0() {
  asm volatile("s_waitcnt vmcnt(0)" ::: "memory");
  __builtin_amdgcn_sched_barrier(0);
}
__device__ __forceinline__ void barrier_only() {
  __builtin_amdgcn_sched_barrier(0);
  __builtin_amdgcn_s_barrier();
  __builtin_amdgcn_sched_barrier(0);
}
__device__ __forceinline__ void lgkm0_barrier() {
  asm volatile("s_waitcnt lgkmcnt(0)" ::: "memory");
  __builtin_amdgcn_sched_barrier(0);
  __builtin_amdgcn_s_barrier();
  __builtin_amdgcn_sched_barrier(0);
}

__global__ void cvt_kernel(const float* __restrict__ src,
                           unsigned short* __restrict__ dst, int n4) {
  int stride = gridDim.x * blockDim.x;
  for (int i = blockIdx.x * blockDim.x + threadIdx.x; i < n4; i += stride) {
    float4 v = reinterpret_cast<const float4*>(src)[i];
    ushort4 o = make_ushort4(f2bf(v.x), f2bf(v.y), f2bf(v.z), f2bf(v.w));
    reinterpret_cast<ushort4*>(dst)[i] = o;
  }
}

__global__ void route_kernel(const int* __restrict__ gidx,
                             int* __restrict__ rows,
                             int* __restrict__ offsets,
                             int2* __restrict__ tiles) {
  __shared__ int cnt[E_], cur[E_];
  int tid = threadIdx.x;
  if (tid < E_) cnt[tid] = 0;
  __syncthreads();
  for (int p = tid; p < NP_; p += blockDim.x) atomicAdd(&cnt[gidx[p]], 1);
  __syncthreads();
  if (tid == 0) {
    int acc = 0;
    for (int e = 0; e < E_; ++e) { offsets[e] = acc; cur[e] = acc; acc += cnt[e]; }
    offsets[E_] = acc;
    int k = 0;
    for (int e = 0; e < E_; ++e)
      for (int m = offsets[e]; m < offsets[e] + cnt[e]; m += 128)
        tiles[k++] = make_int2(e, m);
    for (; k < MTS_; ++k) tiles[k] = make_int2(-1, 0);
  }
  __syncthreads();
  for (int p = tid; p < NP_; p += blockDim.x) {
    int e = gidx[p];
    int pos = atomicAdd(&cur[e], 1);
    rows[pos] = p;
  }
}

#define GLOAD16(g, l)                                                        \
  __builtin_amdgcn_global_load_lds(                                          \
      (const __attribute__((address_space(1))) unsigned int*)(const void*)(g), \
      (__attribute__((address_space(3))) unsigned int*)(void*)(l), 16, 0, 0)

// NT GEMM: 128(M)x64(N) tile, BK=64, 4 waves as 2x2 (each 64x32).
// A (bf16) via global_load_lds, source-side XOR swizzle (verified R2-R4).
// B (f32) reg-staged depth-3, cvt to bf16, ds_write with same XOR swizzle.
// Pipeline: 3 LDS buffers; per K-step wait vmcnt(16) -> tile t's 8 vmem ops
// fly for 2 full compute steps before use.
template<bool IS1>
__global__ __launch_bounds__(256, 2)
void moe_gemm(const unsigned short* __restrict__ A0,   // xb (IS1) or h
              const float* __restrict__ W,             // w1 or w2 (f32)
              const float* __restrict__ bias,          // b1 or b2  [E][NN]
              const int* __restrict__ rows,
              const int* __restrict__ offsets,
              const int2* __restrict__ tiles,
              const float* __restrict__ score,         // [T*K]
              unsigned short* __restrict__ Hout,       // h (IS1)
              float* __restrict__ Yout)                // y (!IS1)
{
  constexpr int BM = 128, BN = 64, BK = 64;
  constexpr int KD = IS1 ? D_ : H_;   // contraction dim
  constexpr int NN = IS1 ? H_ : D_;   // output cols
  constexpr int NT = KD / BK;         // 16 or 32

  const int2 tile = tiles[blockIdx.y];
  const int e = tile.x;
  if (e < 0) return;
  const int s0   = tile.y;
  const int send = offsets[e + 1];
  const int n0   = blockIdx.x * BN;

  __shared__ unsigned short As[3][BM][BK];   // XOR-slot swizzled
  __shared__ unsigned short Bs[3][BN][BK];   // XOR-slot swizzled
  __shared__ int rowsrc[BM];
  __shared__ int rowdst[BM];

  const int tid  = threadIdx.x;
  const int lane = tid & 63;
  const int wid  = tid >> 6;

  if (tid < BM) {
    int s = s0 + tid;
    bool v = s < send;
    int sc2 = v ? s : s0;
    if (IS1) {
      rowsrc[tid] = rows[sc2] >> 1;   // token id (K_=2)
      rowdst[tid] = v ? s : -1;       // h row (routed order)
    } else {
      rowsrc[tid] = sc2;              // h row
      rowdst[tid] = v ? rows[s] : -1; // pair id for scatter + score
    }
  }
  __syncthreads();

  // A staging: per wave 4 x global_load_lds(16B), 8 rows each; LDS dest
  // linear, SOURCE slot pre-XOR'd: LDS[row][s] holds global slot s^(row&7).
  const int arow  = lane >> 3;
  const int aslot = (lane & 7) ^ arow;
  const unsigned short* gA[4];
#pragma unroll
  for (int i = 0; i < 4; ++i)
    gA[i] = A0 + (size_t)rowsrc[wid * 32 + i * 8 + arow] * KD + aslot * 8;

  // B staging: thread t -> row t>>2 (0..63), 16-col seg (t&3). 4 float4 loads.
  const int brow = tid >> 2, bseg = tid & 3;
  const float* gB = W + (size_t)e * NN * KD + (size_t)(n0 + brow) * KD + bseg * 16;

  const int wr = wid >> 1, wc = wid & 1;
  const int fr = lane & 15, fh = lane >> 4;

  f32x4 acc[4][2] = {};
  float4 breg0[4], breg1[4], breg2[4];
  float4* const bregs[3] = {breg0, breg1, breg2};

  auto issueA = [&](int buf, int kk) {
#pragma unroll
    for (int i = 0; i < 4; ++i)
      GLOAD16(gA[i] + kk, &As[buf][wid * 32 + i * 8][0]);
  };
  auto issueB = [&](float4* br, int kk) {
#pragma unroll
    for (int j = 0; j < 4; ++j)
      br[j] = *reinterpret_cast<const float4*>(gB + kk + j * 4);
  };
  auto writeB = [&](int buf, const float4* br) {
#pragma unroll
    for (int j = 0; j < 2; ++j) {
      short8 v;
#pragma unroll
      for (int q = 0; q < 4; ++q) v[q]     = (short)f2bf((&br[2*j].x)[q]);
#pragma unroll
      for (int q = 0; q < 4; ++q) v[4 + q] = (short)f2bf((&br[2*j+1].x)[q]);
      int slot = (bseg * 2 + j) ^ (brow & 7);
      *reinterpret_cast<short8*>(&Bs[buf][brow][slot * 8]) = v;
    }
  };
  auto compute = [&](int buf) {
    short8 af[4][2], bv[2][2];
#pragma unroll
    for (int mi = 0; mi < 4; ++mi) {
      const int row = wr * 64 + mi * 16 + fr;
#pragma unroll
      for (int ks = 0; ks < 2; ++ks) {
        const int slot = (ks * 4 + fh) ^ (row & 7);
        af[mi][ks] = *reinterpret_cast<const short8*>(&As[buf][row][slot * 8]);
      }
    }
#pragma unroll
    for (int ni = 0; ni < 2; ++ni) {
      const int row = wc * 32 + ni * 16 + fr;
#pragma unroll
      for (int ks = 0; ks < 2; ++ks) {
        const int slot = (ks * 4 + fh) ^ (row & 7);
        bv[ni][ks] = *reinterpret_cast<const short8*>(&Bs[buf][row][slot * 8]);
      }
    }
#pragma unroll
    for (int ks = 0; ks < 2; ++ks)
#pragma unroll
      for (int mi = 0; mi < 4; ++mi)
#pragma unroll
        for (int ni = 0; ni < 2; ++ni)
          acc[mi][ni] = __builtin_amdgcn_mfma_f32_16x16x32_bf16(
              af[mi][ks], bv[ni][ks], acc[mi][ni], 0, 0, 0);
  };

  // Prologue: issue tiles 0,1,2 (24 vmem ops in flight).
  issueA(0, 0);        issueB(breg0, 0);
  issueA(1, BK);       issueB(breg1, BK);
  issueA(2, 2 * BK);   issueB(breg2, 2 * BK);

  // Per step t (slot S = t%3):
  //   wait tile t's vmem (outstanding after wait = tiles t+1,t+2 = 16 ops)
  //   writeB(S); lgkm+barrier; compute(S); barrier; issue tile t+3 -> slot S.
  auto body = [&](int t, auto Sc) {
    constexpr int S = decltype(Sc)::value;
    if (t + 2 < NT)      waitv16();
    else if (t + 1 < NT) waitv8();
    else                 waitv0();
    writeB(S, bregs[S]);
    lgkm0_barrier();
    compute(S);
    barrier_only();
    if (t + 3 < NT) { issueA(S, (t + 3) * BK); issueB(bregs[S], (t + 3) * BK); }
  };
  for (int t = 0; t < NT; t += 3) {
    body(t, std::integral_constant<int, 0>{});
    if (t + 1 < NT) body(t + 1, std::integral_constant<int, 1>{});
    if (t + 2 < NT) body(t + 2, std::integral_constant<int, 2>{});
  }

  // Epilogue. C/D map: row = (lane>>4)*4 + j, col = lane&15 (m89-verified).
  const float* biasE = bias + (size_t)e * NN + n0;
#pragma unroll
  for (int mi = 0; mi < 4; ++mi) {
#pragma unroll
    for (int j = 0; j < 4; ++j) {
      int rt  = wr * 64 + mi * 16 + fh * 4 + j;
      int dst = rowdst[rt];
      if (dst < 0) continue;
      float sc = IS1 ? 0.f : score[dst];
#pragma unroll
      for (int ni = 0; ni < 2; ++ni) {
        int col = wc * 32 + ni * 16 + fr;
        float v = acc[mi][ni][j] + biasE[col];
        if (IS1) {
          Hout[(size_t)dst * H_ + n0 + col] = f2bf(gelu_f(v));
        } else {
          Yout[(size_t)dst * D_ + n0 + col] = v * sc;
        }
      }
    }
  }
}

__global__ void combine_kernel(const float* __restrict__ y,
                               float* __restrict__ out) {
  const int DQ = D_ / 4;
  int i = blockIdx.x * blockDim.x + threadIdx.x;   // [0, T_*D_/4)
  int t = i / DQ, d = i % DQ;
  const float4* y4 = reinterpret_cast<const float4*>(y);
  float4 a = y4[(size_t)(2 * t) * DQ + d];
  float4 b = y4[(size_t)(2 * t + 1) * DQ + d];
  reinterpret_cast<float4*>(out)[i] =
      make_float4(a.x + b.x, a.y + b.y, a.z + b.z, a.w + b.w);
}

extern "C" void kernel_launch(void* const* d_in, const int* in_sizes, int n_in,
                              void* d_out, int out_size, void* d_ws, size_t ws_size,
                              hipStream_t stream) {
  const float* inp    = (const float*)d_in[0];
  const int*   gidx   = (const int*)d_in[1];
  const float* gscore = (const float*)d_in[2];
  const float* w1     = (const float*)d_in[3];
  const float* b1     = (const float*)d_in[4];
  const float* w2     = (const float*)d_in[5];
  const float* b2     = (const float*)d_in[6];
  float* out = (float*)d_out;

  char* ws = (char*)d_ws;
  size_t o = 0;
  auto alloc = [&](size_t bytes) {
    void* p = ws + o;
    o = (o + bytes + 255) & ~(size_t)255;
    return p;
  };
  unsigned short* xb   = (unsigned short*)alloc((size_t)T_ * D_ * 2);
  unsigned short* hbuf = (unsigned short*)alloc((size_t)NP_ * H_ * 2);
  float*          ybuf = (float*)alloc((size_t)NP_ * D_ * 4);
  int*            rows = (int*)alloc(NP_ * 4);
  int*         offsets = (int*)alloc((E_ + 1) * 4);
  int2*          tiles = (int2*)alloc(MTS_ * 8);

  cvt_kernel<<<dim3(512), dim3(256), 0, stream>>>(inp, xb, T_ * D_ / 4);
  route_kernel<<<dim3(1), dim3(256), 0, stream>>>(gidx, rows, offsets, tiles);

  moe_gemm<true><<<dim3(H_ / 64, MTS_), dim3(256), 0, stream>>>(
      xb, w1, b1, rows, offsets, tiles, gscore, hbuf, (float*)nullptr);
  moe_gemm<false><<<dim3(D_ / 64, MTS_), dim3(256), 0, stream>>>(
      hbuf, w2, b2, rows, offsets, tiles, gscore, (unsigned short*)nullptr, ybuf);

  combine_kernel<<<dim3(T_ * D_ / 4 / 256), dim3(256), 0, stream>>>(ybuf, out);
}

// Round 9
// 147.284 us; speedup vs baseline: 2.4505x; 1.3329x over previous
//
#include <hip/hip_runtime.h>
#include <hip/hip_bf16.h>
#include <stdint.h>

// MoE (E=16, D=1024, H=2048, K=2, T=2048), routed bf16-MFMA.
// R9 = R4 structure (best: 157us total) with LINE-EFFICIENT B staging:
// every global load instruction touches full 128B cache lines
// (thread t -> row t>>3, octet t&7: 8 rows x 128B contiguous per wave-instr,
// 8 lines/KB = optimal), vs R4's 16 rows x 4 scattered 16B pieces
// (~32 lines/KB). A staging (global_load_lds, 1KB contiguous) unchanged.
// 2 LDS buffers (49KB) -> 3 blocks/CU; counted vmcnt(8) pipeline.

#define E_ 16
#define D_ 1024
#define H_ 2048
#define K_ 2
#define T_ 2048
#define NP_ (T_ * K_)     // 4096 token-expert pairs
#define MTS_ 48           // max M-tiles: sum ceil(ne/128) <= 48

using short8 = __attribute__((ext_vector_type(8))) short;
using f32x4  = __attribute__((ext_vector_type(4))) float;

__device__ __forceinline__ unsigned short f2bf(float f) {
  union { float f; unsigned u; } x; x.f = f;
  unsigned r = x.u + 0x7fffu + ((x.u >> 16) & 1u);   // RNE
  return (unsigned short)(r >> 16);
}

// gelu(tanh approx) = x * sigmoid(1.595769...*(x + 0.044715 x^3))
__device__ __forceinline__ float gelu_f(float x) {
  float u = 1.5957691216057308f * (x + 0.044715f * x * x * x);
  return x / (1.f + __expf(-u));
}

__device__ __forceinline__ void waitv8() {
  asm volatile("s_waitcnt vmcnt(8)" ::: "memory");
  __builtin_amdgcn_sched_barrier(0);
}
__device__ __forceinline__ void waitv0() {
  asm volatile("s_waitcnt vmcnt(0)" ::: "memory");
  __builtin_amdgcn_sched_barrier(0);
}
__device__ __forceinline__ void barrier_only() {
  __builtin_amdgcn_sched_barrier(0);
  __builtin_amdgcn_s_barrier();
  __builtin_amdgcn_sched_barrier(0);
}
__device__ __forceinline__ void lgkm0_barrier() {
  asm volatile("s_waitcnt lgkmcnt(0)" ::: "memory");
  __builtin_amdgcn_sched_barrier(0);
  __builtin_amdgcn_s_barrier();
  __builtin_amdgcn_sched_barrier(0);
}

__global__ void cvt_kernel(const float* __restrict__ src,
                           unsigned short* __restrict__ dst, int n4) {
  int stride = gridDim.x * blockDim.x;
  for (int i = blockIdx.x * blockDim.x + threadIdx.x; i < n4; i += stride) {
    float4 v = reinterpret_cast<const float4*>(src)[i];
    ushort4 o = make_ushort4(f2bf(v.x), f2bf(v.y), f2bf(v.z), f2bf(v.w));
    reinterpret_cast<ushort4*>(dst)[i] = o;
  }
}

__global__ void route_kernel(const int* __restrict__ gidx,
                             int* __restrict__ rows,
                             int* __restrict__ offsets,
                             int2* __restrict__ tiles) {
  __shared__ int cnt[E_], cur[E_];
  int tid = threadIdx.x;
  if (tid < E_) cnt[tid] = 0;
  __syncthreads();
  for (int p = tid; p < NP_; p += blockDim.x) atomicAdd(&cnt[gidx[p]], 1);
  __syncthreads();
  if (tid == 0) {
    int acc = 0;
    for (int e = 0; e < E_; ++e) { offsets[e] = acc; cur[e] = acc; acc += cnt[e]; }
    offsets[E_] = acc;
    int k = 0;
    for (int e = 0; e < E_; ++e)
      for (int m = offsets[e]; m < offsets[e] + cnt[e]; m += 128)
        tiles[k++] = make_int2(e, m);
    for (; k < MTS_; ++k) tiles[k] = make_int2(-1, 0);
  }
  __syncthreads();
  for (int p = tid; p < NP_; p += blockDim.x) {
    int e = gidx[p];
    int pos = atomicAdd(&cur[e], 1);
    rows[pos] = p;
  }
}

#define GLOAD16(g, l)                                                        \
  __builtin_amdgcn_global_load_lds(                                          \
      (const __attribute__((address_space(1))) unsigned int*)(const void*)(g), \
      (__attribute__((address_space(3))) unsigned int*)(void*)(l), 16, 0, 0)

// NT GEMM: 128(M)x64(N) tile, BK=64, 4 waves as 2x2 (each 64x32).
// A (bf16) via global_load_lds, source-side XOR swizzle (verified R2-R4).
// B (f32) reg-staged LINE-EFFICIENT, cvt to bf16, ds_write XOR-swizzled.
template<bool IS1>
__global__ __launch_bounds__(256, 3)
void moe_gemm(const unsigned short* __restrict__ A0,   // xb (IS1) or h
              const float* __restrict__ W,             // w1 or w2 (f32)
              const float* __restrict__ bias,          // b1 or b2  [E][NN]
              const int* __restrict__ rows,
              const int* __restrict__ offsets,
              const int2* __restrict__ tiles,
              const float* __restrict__ score,         // [T*K]
              unsigned short* __restrict__ Hout,       // h (IS1)
              float* __restrict__ Yout)                // y (!IS1)
{
  constexpr int BM = 128, BN = 64, BK = 64;
  constexpr int KD = IS1 ? D_ : H_;   // contraction dim
  constexpr int NN = IS1 ? H_ : D_;   // output cols
  constexpr int NT = KD / BK;         // 16 or 32 (even)

  const int2 tile = tiles[blockIdx.y];
  const int e = tile.x;
  if (e < 0) return;
  const int s0   = tile.y;
  const int send = offsets[e + 1];
  const int n0   = blockIdx.x * BN;

  __shared__ unsigned short As[2][BM][BK];   // XOR-slot swizzled
  __shared__ unsigned short Bs[2][BN][BK];   // XOR-slot swizzled
  __shared__ int rowsrc[BM];
  __shared__ int rowdst[BM];

  const int tid  = threadIdx.x;
  const int lane = tid & 63;
  const int wid  = tid >> 6;

  if (tid < BM) {
    int s = s0 + tid;
    bool v = s < send;
    int sc2 = v ? s : s0;
    if (IS1) {
      rowsrc[tid] = rows[sc2] >> 1;   // token id (K_=2)
      rowdst[tid] = v ? s : -1;       // h row (routed order)
    } else {
      rowsrc[tid] = sc2;              // h row
      rowdst[tid] = v ? rows[s] : -1; // pair id for scatter + score
    }
  }
  __syncthreads();

  // A staging: per wave 4 x global_load_lds(16B), 8 rows each; LDS dest
  // linear, SOURCE slot pre-XOR'd: LDS[row][s] holds global slot s^(row&7).
  const int arow  = lane >> 3;
  const int aslot = (lane & 7) ^ arow;
  const unsigned short* gA[4];
#pragma unroll
  for (int i = 0; i < 4; ++i)
    gA[i] = A0 + (size_t)rowsrc[wid * 32 + i * 8 + arow] * KD + aslot * 8;

  // B staging, line-efficient: thread t -> row (t>>3) & 31, octet t&7.
  // Each wave-instr = 8 consecutive rows x 128B contiguous (8 full lines).
  // 4 float4/thread/K-step: (row, row+32) x (col oct*16B, +128B).
  const int brow = tid >> 3;          // 0..31
  const int boct = tid & 7;
  const float* gB0 = W + (size_t)e * NN * KD + (size_t)(n0 + brow) * KD + boct * 4;
  const float* gB2 = gB0 + (size_t)32 * KD;

  const int wr = wid >> 1, wc = wid & 1;
  const int fr = lane & 15, fh = lane >> 4;

  f32x4 acc[4][2] = {};
  float4 breg0[4], breg1[4];

  auto issueA = [&](int buf, int kk) {
#pragma unroll
    for (int i = 0; i < 4; ++i)
      GLOAD16(gA[i] + kk, &As[buf][wid * 32 + i * 8][0]);
  };
  auto issueB = [&](float4* br, int kk) {
    br[0] = *reinterpret_cast<const float4*>(gB0 + kk);
    br[1] = *reinterpret_cast<const float4*>(gB0 + kk + 32);
    br[2] = *reinterpret_cast<const float4*>(gB2 + kk);
    br[3] = *reinterpret_cast<const float4*>(gB2 + kk + 32);
  };
  // piece (row, kl0): 4 shorts at swizzled addr; slot=(kl0>>3)^(row&7).
  auto writeB = [&](int buf, const float4* br) {
#pragma unroll
    for (int p = 0; p < 4; ++p) {
      int row = (p & 2) ? brow + 32 : brow;
      int kl0 = boct * 4 + ((p & 1) ? 32 : 0);
      ushort4 u;
      const float* f = &br[p].x;
      u.x = f2bf(f[0]); u.y = f2bf(f[1]); u.z = f2bf(f[2]); u.w = f2bf(f[3]);
      int idx = (((kl0 >> 3) ^ (row & 7)) << 3) + (kl0 & 7);
      *reinterpret_cast<ushort4*>(&Bs[buf][row][idx]) = u;
    }
  };
  auto compute = [&](int buf) {
    short8 af[4][2], bv[2][2];
#pragma unroll
    for (int mi = 0; mi < 4; ++mi) {
      const int row = wr * 64 + mi * 16 + fr;
#pragma unroll
      for (int ks = 0; ks < 2; ++ks) {
        const int slot = (ks * 4 + fh) ^ (row & 7);
        af[mi][ks] = *reinterpret_cast<const short8*>(&As[buf][row][slot * 8]);
      }
    }
#pragma unroll
    for (int ni = 0; ni < 2; ++ni) {
      const int row = wc * 32 + ni * 16 + fr;
#pragma unroll
      for (int ks = 0; ks < 2; ++ks) {
        const int slot = (ks * 4 + fh) ^ (row & 7);
        bv[ni][ks] = *reinterpret_cast<const short8*>(&Bs[buf][row][slot * 8]);
      }
    }
#pragma unroll
    for (int ks = 0; ks < 2; ++ks)
#pragma unroll
      for (int mi = 0; mi < 4; ++mi)
#pragma unroll
        for (int ni = 0; ni < 2; ++ni)
          acc[mi][ni] = __builtin_amdgcn_mfma_f32_16x16x32_bf16(
              af[mi][ks], bv[ni][ks], acc[mi][ni], 0, 0, 0);
  };

  // Prologue: issue tiles 0,1 (16 vmem ops/wave), land tile 0.
  issueA(0, 0);       issueB(breg0, 0);
  issueA(1, BK);      issueB(breg1, BK);
  waitv8();                       // tile-0 ops (oldest 8) complete
  writeB(0, breg0);
  lgkm0_barrier();                // all waves: tile 0 fully in LDS

  for (int t = 0; t < NT; t += 2) {
    // ---- step t (buffers 0) ----
    compute(0);
    barrier_only();               // all waves done reading LDS[0]
    if (t + 2 < NT) {
      issueA(0, (t + 2) * BK); issueB(breg0, (t + 2) * BK);
      waitv8();                   // {t+1} ops complete
    } else {
      waitv0();
    }
    writeB(1, breg1);
    lgkm0_barrier();              // all waves: tile t+1 fully in LDS
    // ---- step t+1 (buffers 1) ----
    compute(1);
    barrier_only();               // all waves done reading LDS[1]
    if (t + 2 < NT) {
      if (t + 3 < NT) { issueA(1, (t + 3) * BK); issueB(breg1, (t + 3) * BK); waitv8(); }
      else            { waitv0(); }
      writeB(0, breg0);
      lgkm0_barrier();            // all waves: tile t+2 fully in LDS
    }
  }

  // Epilogue. C/D map: row = (lane>>4)*4 + j, col = lane&15 (m89-verified).
  const float* biasE = bias + (size_t)e * NN + n0;
#pragma unroll
  for (int mi = 0; mi < 4; ++mi) {
#pragma unroll
    for (int j = 0; j < 4; ++j) {
      int rt  = wr * 64 + mi * 16 + fh * 4 + j;
      int dst = rowdst[rt];
      if (dst < 0) continue;
      float sc = IS1 ? 0.f : score[dst];
#pragma unroll
      for (int ni = 0; ni < 2; ++ni) {
        int col = wc * 32 + ni * 16 + fr;
        float v = acc[mi][ni][j] + biasE[col];
        if (IS1) {
          Hout[(size_t)dst * H_ + n0 + col] = f2bf(gelu_f(v));
        } else {
          Yout[(size_t)dst * D_ + n0 + col] = v * sc;
        }
      }
    }
  }
}

__global__ void combine_kernel(const float* __restrict__ y,
                               float* __restrict__ out) {
  const int DQ = D_ / 4;
  int i = blockIdx.x * blockDim.x + threadIdx.x;   // [0, T_*D_/4)
  int t = i / DQ, d = i % DQ;
  const float4* y4 = reinterpret_cast<const float4*>(y);
  float4 a = y4[(size_t)(2 * t) * DQ + d];
  float4 b = y4[(size_t)(2 * t + 1) * DQ + d];
  reinterpret_cast<float4*>(out)[i] =
      make_float4(a.x + b.x, a.y + b.y, a.z + b.z, a.w + b.w);
}

extern "C" void kernel_launch(void* const* d_in, const int* in_sizes, int n_in,
                              void* d_out, int out_size, void* d_ws, size_t ws_size,
                              hipStream_t stream) {
  const float* inp    = (const float*)d_in[0];
  const int*   gidx   = (const int*)d_in[1];
  const float* gscore = (const float*)d_in[2];
  const float* w1     = (const float*)d_in[3];
  const float* b1     = (const float*)d_in[4];
  const float* w2     = (const float*)d_in[5];
  const float* b2     = (const float*)d_in[6];
  float* out = (float*)d_out;

  char* ws = (char*)d_ws;
  size_t o = 0;
  auto alloc = [&](size_t bytes) {
    void* p = ws + o;
    o = (o + bytes + 255) & ~(size_t)255;
    return p;
  };
  unsigned short* xb   = (unsigned short*)alloc((size_t)T_ * D_ * 2);
  unsigned short* hbuf = (unsigned short*)alloc((size_t)NP_ * H_ * 2);
  float*          ybuf = (float*)alloc((size_t)NP_ * D_ * 4);
  int*            rows = (int*)alloc(NP_ * 4);
  int*         offsets = (int*)alloc((E_ + 1) * 4);
  int2*          tiles = (int2*)alloc(MTS_ * 8);

  cvt_kernel<<<dim3(512), dim3(256), 0, stream>>>(inp, xb, T_ * D_ / 4);
  route_kernel<<<dim3(1), dim3(256), 0, stream>>>(gidx, rows, offsets, tiles);

  moe_gemm<true><<<dim3(H_ / 64, MTS_), dim3(256), 0, stream>>>(
      xb, w1, b1, rows, offsets, tiles, gscore, hbuf, (float*)nullptr);
  moe_gemm<false><<<dim3(D_ / 64, MTS_), dim3(256), 0, stream>>>(
      hbuf, w2, b2, rows, offsets, tiles, gscore, (unsigned short*)nullptr, ybuf);

  combine_kernel<<<dim3(T_ * D_ / 4 / 256), dim3(256), 0, stream>>>(ybuf, out);
}